// Round 7
// baseline (462.420 us; speedup 1.0000x reference)
//
#include <hip/hip_runtime.h>

#define N_TOT   500000
#define M_Q     1024
#define QB      16
#define NSPLIT  16
#define CAND_MAX 8192

#define ARGMIN_BLKS 1024            // 64 query-tiles x 16 N-splits
#define HIST_BLKS   32
#define USAGE_BLKS  64
#define SMALL_BLKS  (ARGMIN_BLKS + HIST_BLKS + USAGE_BLKS)
#define HIST_CHUNK  (N_TOT / HIST_BLKS)   // 15625

#define COPY_GRID   2048
#define MPTS_GRID   512

static const unsigned OUT_ROWS  = 259u * (unsigned)N_TOT;     // 129,500,000
static const unsigned OUT_USAGE = OUT_ROWS;
static const unsigned OUT_IDX   = OUT_ROWS + (unsigned)N_TOT; // 130,000,000

// ---- ws layout (bytes) ----
#define WS_PARTKEY 0                 // M*NSPLIT f32 = 65536
#define WS_PARTIDX 65536             // M*NSPLIT i32 = 65536
#define WS_HISTP   131072            // 32*1024 i32  = 131072 (plain stores, no zeroing)
#define WS_V       262144            // 1 i32
#define WS_CNT     262148            // 1 i32
#define WS_KEYS    262152            // CAND_MAX u32 = 32768

// ============  flat copy: m13-style grid-stride, deep per-thread loop  =============
__global__ __launch_bounds__(256) void k_copy_flat(
    const float* __restrict__ mdesc, float* __restrict__ out)
{
    const unsigned TOT4 = (unsigned)N_TOT * 64u;          // 32,000,000 float4s
    const unsigned stride = COPY_GRID * 256u;             // 524,288
    unsigned g0 = blockIdx.x * 256u + threadIdx.x;
#pragma unroll 4
    for (unsigned g = g0; g < TOT4; g += stride) {
        float4 v = *reinterpret_cast<const float4*>(mdesc + (size_t)g * 4u);
        unsigned n = g >> 6;                              // row
        unsigned c = (g & 63u) << 2;                      // col within 256
        *reinterpret_cast<float4*>(out + (size_t)n * 259u + 3u + c) = v;
    }
}

// ============  mpts columns (0..2) of each output row  =============================
__global__ __launch_bounds__(256) void k_mpts(
    const float* __restrict__ mpts, float* __restrict__ out)
{
    const int TOT = N_TOT * 3;                            // 1,500,000
    const int stride = MPTS_GRID * 256;
    for (int g = blockIdx.x * 256 + threadIdx.x; g < TOT; g += stride) {
        int n = g / 3;                                    // magic-div by compiler
        int r = g - n * 3;
        out[(size_t)n * 259u + r] = mpts[g];
    }
}

// ============  SMALL mega: argmin || hist || usage-copy  ===========================
__global__ __launch_bounds__(256) void k_small(
    const float* __restrict__ pts,  const float* __restrict__ mpts,
    const int* __restrict__ usage,
    float* __restrict__ out,
    float* __restrict__ partKey, int* __restrict__ partIdx,
    int* __restrict__ histPart)
{
    __shared__ int smem[1024];
    const int b   = blockIdx.x;
    const int tid = threadIdx.x;

    if (b < ARGMIN_BLKS) {
        // ---------------- argmin role (math identical since R1: absmax 0) ----------
        const int qb = b & 63;
        const int ns = b >> 6;
        const int qbase = qb * QB;
        const int chunk = N_TOT / NSPLIT;   // 31250
        const int n0 = ns * chunk;
        const int n1 = n0 + chunk;

        float* qs = (float*)smem;           // 48 floats
        float* wk = (float*)smem + 64;      // [4][16]
        int*   wi = smem + 192;             // [4][16]
        if (tid < QB * 3) qs[tid] = pts[qbase * 3 + tid];
        __syncthreads();

        float qx[QB], qy[QB], qz[QB];
#pragma unroll
        for (int i = 0; i < QB; i++) { qx[i] = qs[3*i]; qy[i] = qs[3*i+1]; qz[i] = qs[3*i+2]; }

        float bk[QB]; int bi[QB];
#pragma unroll
        for (int i = 0; i < QB; i++) { bk[i] = INFINITY; bi[i] = 0x7fffffff; }

        for (int n = n0 + tid; n < n1; n += 256) {
            float x = mpts[3*n+0], y = mpts[3*n+1], z = mpts[3*n+2];
            float h = 0.5f * (x*x + y*y + z*z);
#pragma unroll
            for (int i = 0; i < QB; i++) {
                float key = h - x*qx[i] - y*qy[i] - z*qz[i];
                bool lt = key < bk[i];      // strict < + ascending n => first-min kept
                bk[i] = lt ? key : bk[i];
                bi[i] = lt ? n   : bi[i];
            }
        }

        const int lane = tid & 63;
        const int wv   = tid >> 6;
#pragma unroll
        for (int off = 32; off > 0; off >>= 1) {
#pragma unroll
            for (int i = 0; i < QB; i++) {
                float ok = __shfl_down(bk[i], off, 64);
                int   oi = __shfl_down(bi[i], off, 64);
                if (ok < bk[i] || (ok == bk[i] && oi < bi[i])) { bk[i] = ok; bi[i] = oi; }
            }
        }
        if (lane == 0) {
#pragma unroll
            for (int i = 0; i < QB; i++) { wk[wv*QB + i] = bk[i]; wi[wv*QB + i] = bi[i]; }
        }
        __syncthreads();
        if (tid < QB) {
            float k = wk[tid]; int ix = wi[tid];
#pragma unroll
            for (int w = 1; w < 4; w++) {
                float ok = wk[w*QB + tid]; int oi = wi[w*QB + tid];
                if (ok < k || (ok == k && oi < ix)) { k = ok; ix = oi; }
            }
            partKey[(qbase + tid) * NSPLIT + ns] = k;
            partIdx[(qbase + tid) * NSPLIT + ns] = ix;
        }
    } else if (b < ARGMIN_BLKS + HIST_BLKS) {
        // ---------------- hist role: per-block partial histogram -------------------
        const int hb = b - ARGMIN_BLKS;
        const int r0 = hb * HIST_CHUNK;
        const int r1 = r0 + HIST_CHUNK;
#pragma unroll
        for (int i = 0; i < 4; i++) smem[tid + i * 256] = 0;
        __syncthreads();
        for (int n = r0 + tid; n < r1; n += 256) {
            unsigned v = (unsigned)usage[n];
            if (v > 1023u) v = 1023u;
            atomicAdd(&smem[v], 1);
        }
        __syncthreads();
#pragma unroll
        for (int i = 0; i < 4; i++) {
            int bin = tid + i * 256;
            histPart[hb * 1024 + bin] = smem[bin];
        }
    } else {
        // ---------------- usage-as-float role (int4 -> float4) ---------------------
        const int ub = b - ARGMIN_BLKS - HIST_BLKS;
        const int4* u4 = (const int4*)usage;
        float4* o4 = (float4*)(out + OUT_USAGE);    // offset %4==0: 16B-aligned
        const int TOT4 = N_TOT / 4;                 // 125000
        for (int g = ub * 256 + tid; g < TOT4; g += USAGE_BLKS * 256) {
            int4 u = u4[g];
            o4[g] = make_float4((float)u.x, (float)u.y, (float)u.z, (float)u.w);
        }
    }
}

// =====================  scanV: total hist, scan, cutoff V, zero cnt  ===============
__global__ __launch_bounds__(1024) void k_scanV(
    const int* __restrict__ histPart, int* __restrict__ Vout, int* __restrict__ cnt)
{
    __shared__ int scan[1024];
    const int t = threadIdx.x;
    int h = 0;
#pragma unroll
    for (int b = 0; b < HIST_BLKS; b++) h += histPart[b * 1024 + t];
    scan[t] = h; __syncthreads();
    for (int off = 1; off < 1024; off <<= 1) {
        int add = (t >= off) ? scan[t - off] : 0;
        __syncthreads();
        scan[t] += add;
        __syncthreads();
    }
    int cum  = scan[t] - h;    // count(usage < t)
    int cumN = scan[t];        // count(usage <= t)
    if (cum < M_Q && cumN >= M_Q) { *Vout = t; *cnt = 0; }
}

// =====================  collect candidates (usage <= V), unordered  ================
__global__ __launch_bounds__(256) void k_collect(
    const int* __restrict__ usage, const int* __restrict__ Vp,
    int* __restrict__ cnt, unsigned* __restrict__ keys)
{
    const int V = *Vp;
    const int stride = gridDim.x * 256;
    for (int n = blockIdx.x * 256 + threadIdx.x; n < N_TOT; n += stride) {
        int u = usage[n];
        if (u <= V) {
            int p = atomicAdd(cnt, 1);
            if (p < CAND_MAX) keys[p] = ((unsigned)u << 19) | (unsigned)n;
        }
    }
}

// =====================  final: sort, rank, idx out, usage bump  ====================
__global__ __launch_bounds__(1024) void k_final(
    const float* __restrict__ pts,
    const float* __restrict__ partKey, const int* __restrict__ partIdx,
    const int* __restrict__ cntP, const unsigned* __restrict__ keysG,
    float* __restrict__ out)
{
    __shared__ unsigned keys[CAND_MAX];
    __shared__ int      mscan[1024];
    const int t = threadIdx.x;

    // 1) reduce NSPLIT partials (ascending-n chunk order: strict <)
    float bk = INFINITY; int bi = 0x7fffffff;
#pragma unroll
    for (int s = 0; s < NSPLIT; s++) {
        float k = partKey[t * NSPLIT + s];
        int   i = partIdx[t * NSPLIT + s];
        if (k < bk) { bk = k; bi = i; }
    }
    float px = pts[3*t], py = pts[3*t+1], pz = pts[3*t+2];
    float d2 = px*px + py*py + pz*pz + 2.0f * bk;
    const bool mask = d2 > 1e-6f;   // sqrt(max(d2,1e-12)) > 1e-3

    // 2) load candidates, pad to next pow2 (C >= M_Q by construction of V)
    int C = *cntP; if (C > CAND_MAX) C = CAND_MAX;
    int P2 = 1; while (P2 < C) P2 <<= 1;
    for (int p = t; p < P2; p += 1024) keys[p] = (p < C) ? keysG[p] : 0xFFFFFFFFu;
    __syncthreads();

    // 3) bitonic sort ascending -> (usage asc, index asc) == lax.top_k order
    for (int k = 2; k <= P2; k <<= 1) {
        for (int j = k >> 1; j > 0; j >>= 1) {
            for (int i = t; i < P2; i += 1024) {
                int ixj = i ^ j;
                if (ixj > i) {
                    unsigned a = keys[i], bb = keys[ixj];
                    bool up = ((i & k) == 0);
                    if ((a > bb) == up) { keys[i] = bb; keys[ixj] = a; }
                }
            }
            __syncthreads();
        }
    }

    // 4) rank = cumsum(mask)-1 ; final idx; outputs
    mscan[t] = mask ? 1 : 0; __syncthreads();
    for (int off = 1; off < 1024; off <<= 1) {
        int add = (t >= off) ? mscan[t - off] : 0;
        __syncthreads();
        mscan[t] += add;
        __syncthreads();
    }
    int rank = mscan[t] - 1;
    int idx = mask ? (int)(keys[rank] & 0x7FFFFu) : bi;
    out[(size_t)OUT_IDX + (size_t)t] = (float)idx;
    atomicAdd(out + OUT_USAGE + idx, 1.0f);   // after k_small wrote base usage
}

extern "C" void kernel_launch(void* const* d_in, const int* in_sizes, int n_in,
                              void* d_out, int out_size, void* d_ws, size_t ws_size,
                              hipStream_t stream)
{
    (void)in_sizes; (void)n_in; (void)out_size; (void)ws_size;
    const float* pts   = (const float*)d_in[0];
    const float* mpts  = (const float*)d_in[2];
    const float* mdesc = (const float*)d_in[3];
    const int*   usage = (const int*)d_in[4];
    float* out = (float*)d_out;

    char* ws = (char*)d_ws;
    float*    partKey  = (float*)(ws + WS_PARTKEY);
    int*      partIdx  = (int*)(ws + WS_PARTIDX);
    int*      histPart = (int*)(ws + WS_HISTP);
    int*      Vp       = (int*)(ws + WS_V);
    int*      cnt      = (int*)(ws + WS_CNT);
    unsigned* keys     = (unsigned*)(ws + WS_KEYS);

    k_copy_flat<<<COPY_GRID, 256, 0, stream>>>(mdesc, out);
    k_mpts<<<MPTS_GRID, 256, 0, stream>>>(mpts, out);
    k_small<<<SMALL_BLKS, 256, 0, stream>>>(pts, mpts, usage, out,
                                            partKey, partIdx, histPart);
    k_scanV<<<1, 1024, 0, stream>>>(histPart, Vp, cnt);
    k_collect<<<64, 256, 0, stream>>>(usage, Vp, cnt, keys);
    k_final<<<1, 1024, 0, stream>>>(pts, partKey, partIdx, cnt, keys, out);
}

// Round 8
// 347.657 us; speedup vs baseline: 1.3301x; 1.3301x over previous
//
#include <hip/hip_runtime.h>

#define N_TOT   500000
#define M_Q     1024
#define QB      16
#define NSPLIT  16
#define CAND_MAX 8192

#define CROWS       16                      // rows per tile
#define NTILES      (N_TOT / CROWS)         // 31250
#define COPY_BLKS   625
#define TILES_PER_B (NTILES / COPY_BLKS)    // 50
#define ARGMIN_BLKS 1024                    // 64 query-tiles x 16 N-splits
#define HIST_BLKS   32
#define USAGE_BLKS  64
#define MEGA_BLKS   (COPY_BLKS + ARGMIN_BLKS + HIST_BLKS + USAGE_BLKS)
#define HIST_CHUNK  (N_TOT / HIST_BLKS)     // 15625

#define TILE_F      (CROWS * 259)           // 4144 floats per tile (16B-aligned)

static const unsigned OUT_ROWS  = 259u * (unsigned)N_TOT;     // 129,500,000
static const unsigned OUT_USAGE = OUT_ROWS;
static const unsigned OUT_IDX   = OUT_ROWS + (unsigned)N_TOT; // 130,000,000

// ---- ws layout (bytes) ----
#define WS_PARTKEY 0                 // M*NSPLIT f32 = 65536
#define WS_PARTIDX 65536             // M*NSPLIT i32 = 65536
#define WS_HISTP   131072            // 32*1024 i32  = 131072 (plain stores, no zeroing)
#define WS_V       262144            // 1 i32
#define WS_CNT     262148            // 1 i32
#define WS_KEYS    262152            // CAND_MAX u32 = 32768

typedef float f4v __attribute__((ext_vector_type(4)));

// =====================  MEGA: row-copy || argmin || hist || usage-copy ==============
__global__ __launch_bounds__(256) void k_mega(
    const float* __restrict__ pts,  const float* __restrict__ mpts,
    const float* __restrict__ mdesc, const int* __restrict__ usage,
    float* __restrict__ out,
    float* __restrict__ partKey, int* __restrict__ partIdx,
    int* __restrict__ histPart)
{
    __shared__ float smem[2 * TILE_F];    // 33152 B (copy dbuf; unioned by other roles)
    const int b   = blockIdx.x;
    const int tid = threadIdx.x;

    if (b < COPY_BLKS) {
        // ------- row-copy role: block-contiguous tiles, aligned both ways, nt stores
        for (int t = 0; t < TILES_PER_B; ++t) {
            const int tile = b * TILES_PER_B + t;
            const int n0   = tile * CROWS;
            float* L = smem + (t & 1) * TILE_F;

            // aligned loads: 1024 float4 of mdesc tile + 48 mpts floats
            const float4* src = (const float4*)(mdesc + (size_t)n0 * 256);
            float4 v[4];
#pragma unroll
            for (int it = 0; it < 4; it++) v[it] = src[tid + it * 256];
            float pv = (tid < CROWS * 3) ? mpts[(size_t)n0 * 3 + tid] : 0.0f;

            // stage as output image [16][259]
#pragma unroll
            for (int it = 0; it < 4; it++) {
                int g = tid + it * 256;
                int r = g >> 6;
                int c = (g & 63) << 2;
                float* d = L + r * 259 + 3 + c;
                d[0] = v[it].x; d[1] = v[it].y; d[2] = v[it].z; d[3] = v[it].w;
            }
            if (tid < CROWS * 3) {
                int r = tid / 3, c = tid - r * 3;
                L[r * 259 + c] = pv;
            }
            __syncthreads();

            // aligned nt stores: 1036 float4 (tile base = tile*4144 floats, %4==0)
            f4v* dst4 = (f4v*)(out + (size_t)tile * TILE_F);
            const f4v* s4 = (const f4v*)L;
#pragma unroll
            for (int it = 0; it < 5; it++) {
                int g = tid + it * 256;
                if (g < TILE_F / 4) __builtin_nontemporal_store(s4[g], dst4 + g);
            }
        }
    } else if (b < COPY_BLKS + ARGMIN_BLKS) {
        // ---------------- argmin role (math identical since R1: absmax 0) ----------
        const int rb = b - COPY_BLKS;
        const int qb = rb & 63;
        const int ns = rb >> 6;
        const int qbase = qb * QB;
        const int chunk = N_TOT / NSPLIT;   // 31250
        const int n0 = ns * chunk;
        const int n1 = n0 + chunk;

        float* qs = smem;                   // 48 floats
        float* wk = smem + 64;              // [4][16]
        int*   wi = (int*)(smem + 192);     // [4][16]
        if (tid < QB * 3) qs[tid] = pts[qbase * 3 + tid];
        __syncthreads();

        float qx[QB], qy[QB], qz[QB];
#pragma unroll
        for (int i = 0; i < QB; i++) { qx[i] = qs[3*i]; qy[i] = qs[3*i+1]; qz[i] = qs[3*i+2]; }

        float bk[QB]; int bi[QB];
#pragma unroll
        for (int i = 0; i < QB; i++) { bk[i] = INFINITY; bi[i] = 0x7fffffff; }

        for (int n = n0 + tid; n < n1; n += 256) {
            float x = mpts[3*n+0], y = mpts[3*n+1], z = mpts[3*n+2];
            float h = 0.5f * (x*x + y*y + z*z);
#pragma unroll
            for (int i = 0; i < QB; i++) {
                float key = h - x*qx[i] - y*qy[i] - z*qz[i];
                bool lt = key < bk[i];      // strict < + ascending n => first-min kept
                bk[i] = lt ? key : bk[i];
                bi[i] = lt ? n   : bi[i];
            }
        }

        const int lane = tid & 63;
        const int wv   = tid >> 6;
#pragma unroll
        for (int off = 32; off > 0; off >>= 1) {
#pragma unroll
            for (int i = 0; i < QB; i++) {
                float ok = __shfl_down(bk[i], off, 64);
                int   oi = __shfl_down(bi[i], off, 64);
                if (ok < bk[i] || (ok == bk[i] && oi < bi[i])) { bk[i] = ok; bi[i] = oi; }
            }
        }
        if (lane == 0) {
#pragma unroll
            for (int i = 0; i < QB; i++) { wk[wv*QB + i] = bk[i]; wi[wv*QB + i] = bi[i]; }
        }
        __syncthreads();
        if (tid < QB) {
            float k = wk[tid]; int ix = wi[tid];
#pragma unroll
            for (int w = 1; w < 4; w++) {
                float ok = wk[w*QB + tid]; int oi = wi[w*QB + tid];
                if (ok < k || (ok == k && oi < ix)) { k = ok; ix = oi; }
            }
            partKey[(qbase + tid) * NSPLIT + ns] = k;
            partIdx[(qbase + tid) * NSPLIT + ns] = ix;
        }
    } else if (b < COPY_BLKS + ARGMIN_BLKS + HIST_BLKS) {
        // ---------------- hist role: per-block partial histogram -------------------
        const int hb = b - COPY_BLKS - ARGMIN_BLKS;
        const int r0 = hb * HIST_CHUNK;
        const int r1 = r0 + HIST_CHUNK;
        int* lh = (int*)smem;
#pragma unroll
        for (int i = 0; i < 4; i++) lh[tid + i * 256] = 0;
        __syncthreads();
        for (int n = r0 + tid; n < r1; n += 256) {
            unsigned v = (unsigned)usage[n];
            if (v > 1023u) v = 1023u;
            atomicAdd(&lh[v], 1);
        }
        __syncthreads();
#pragma unroll
        for (int i = 0; i < 4; i++) {
            int bin = tid + i * 256;
            histPart[hb * 1024 + bin] = lh[bin];
        }
    } else {
        // ---------------- usage-as-float role (int4 -> float4) ---------------------
        const int ub = b - COPY_BLKS - ARGMIN_BLKS - HIST_BLKS;
        const int4* u4 = (const int4*)usage;
        float4* o4 = (float4*)(out + OUT_USAGE);    // offset %4==0: 16B-aligned
        const int TOT4 = N_TOT / 4;                 // 125000
        for (int g = ub * 256 + tid; g < TOT4; g += USAGE_BLKS * 256) {
            int4 u = u4[g];
            o4[g] = make_float4((float)u.x, (float)u.y, (float)u.z, (float)u.w);
        }
    }
}

// =====================  scanV: total hist, scan, cutoff V, zero cnt  ===============
__global__ __launch_bounds__(1024) void k_scanV(
    const int* __restrict__ histPart, int* __restrict__ Vout, int* __restrict__ cnt)
{
    __shared__ int scan[1024];
    const int t = threadIdx.x;
    int h = 0;
#pragma unroll
    for (int b = 0; b < HIST_BLKS; b++) h += histPart[b * 1024 + t];
    scan[t] = h; __syncthreads();
    for (int off = 1; off < 1024; off <<= 1) {
        int add = (t >= off) ? scan[t - off] : 0;
        __syncthreads();
        scan[t] += add;
        __syncthreads();
    }
    int cum  = scan[t] - h;    // count(usage < t)
    int cumN = scan[t];        // count(usage <= t)
    if (cum < M_Q && cumN >= M_Q) { *Vout = t; *cnt = 0; }
}

// =====================  collect candidates (usage <= V), unordered  ================
__global__ __launch_bounds__(256) void k_collect(
    const int* __restrict__ usage, const int* __restrict__ Vp,
    int* __restrict__ cnt, unsigned* __restrict__ keys)
{
    const int V = *Vp;
    const int stride = gridDim.x * 256;
    for (int n = blockIdx.x * 256 + threadIdx.x; n < N_TOT; n += stride) {
        int u = usage[n];
        if (u <= V) {
            int p = atomicAdd(cnt, 1);
            if (p < CAND_MAX) keys[p] = ((unsigned)u << 19) | (unsigned)n;
        }
    }
}

// =====================  final: sort, rank, idx out, usage bump  ====================
__global__ __launch_bounds__(1024) void k_final(
    const float* __restrict__ pts,
    const float* __restrict__ partKey, const int* __restrict__ partIdx,
    const int* __restrict__ cntP, const unsigned* __restrict__ keysG,
    float* __restrict__ out)
{
    __shared__ unsigned keys[CAND_MAX];
    __shared__ int      mscan[1024];
    const int t = threadIdx.x;

    // 1) reduce NSPLIT partials (ascending-n chunk order: strict <)
    float bk = INFINITY; int bi = 0x7fffffff;
#pragma unroll
    for (int s = 0; s < NSPLIT; s++) {
        float k = partKey[t * NSPLIT + s];
        int   i = partIdx[t * NSPLIT + s];
        if (k < bk) { bk = k; bi = i; }
    }
    float px = pts[3*t], py = pts[3*t+1], pz = pts[3*t+2];
    float d2 = px*px + py*py + pz*pz + 2.0f * bk;
    const bool mask = d2 > 1e-6f;   // sqrt(max(d2,1e-12)) > 1e-3

    // 2) load candidates, pad to next pow2 (C >= M_Q by construction of V)
    int C = *cntP; if (C > CAND_MAX) C = CAND_MAX;
    int P2 = 1; while (P2 < C) P2 <<= 1;
    for (int p = t; p < P2; p += 1024) keys[p] = (p < C) ? keysG[p] : 0xFFFFFFFFu;
    __syncthreads();

    // 3) bitonic sort ascending -> (usage asc, index asc) == lax.top_k order
    for (int k = 2; k <= P2; k <<= 1) {
        for (int j = k >> 1; j > 0; j >>= 1) {
            for (int i = t; i < P2; i += 1024) {
                int ixj = i ^ j;
                if (ixj > i) {
                    unsigned a = keys[i], bb = keys[ixj];
                    bool up = ((i & k) == 0);
                    if ((a > bb) == up) { keys[i] = bb; keys[ixj] = a; }
                }
            }
            __syncthreads();
        }
    }

    // 4) rank = cumsum(mask)-1 ; final idx; outputs
    mscan[t] = mask ? 1 : 0; __syncthreads();
    for (int off = 1; off < 1024; off <<= 1) {
        int add = (t >= off) ? mscan[t - off] : 0;
        __syncthreads();
        mscan[t] += add;
        __syncthreads();
    }
    int rank = mscan[t] - 1;
    int idx = mask ? (int)(keys[rank] & 0x7FFFFu) : bi;
    out[(size_t)OUT_IDX + (size_t)t] = (float)idx;
    atomicAdd(out + OUT_USAGE + idx, 1.0f);   // after mega wrote base usage
}

extern "C" void kernel_launch(void* const* d_in, const int* in_sizes, int n_in,
                              void* d_out, int out_size, void* d_ws, size_t ws_size,
                              hipStream_t stream)
{
    (void)in_sizes; (void)n_in; (void)out_size; (void)ws_size;
    const float* pts   = (const float*)d_in[0];
    const float* mpts  = (const float*)d_in[2];
    const float* mdesc = (const float*)d_in[3];
    const int*   usage = (const int*)d_in[4];
    float* out = (float*)d_out;

    char* ws = (char*)d_ws;
    float*    partKey  = (float*)(ws + WS_PARTKEY);
    int*      partIdx  = (int*)(ws + WS_PARTIDX);
    int*      histPart = (int*)(ws + WS_HISTP);
    int*      Vp       = (int*)(ws + WS_V);
    int*      cnt      = (int*)(ws + WS_CNT);
    unsigned* keys     = (unsigned*)(ws + WS_KEYS);

    k_mega<<<MEGA_BLKS, 256, 0, stream>>>(pts, mpts, mdesc, usage, out,
                                          partKey, partIdx, histPart);
    k_scanV<<<1, 1024, 0, stream>>>(histPart, Vp, cnt);
    k_collect<<<64, 256, 0, stream>>>(usage, Vp, cnt, keys);
    k_final<<<1, 1024, 0, stream>>>(pts, partKey, partIdx, cnt, keys, out);
}